// Round 7
// baseline (38.411 us; speedup 1.0000x reference)
//
#include <hip/hip_runtime.h>
#include <hip/hip_bf16.h>

// Problem constants: B=32768, D=768, C=200.
#define NROWS 32768
#define DIMS  768
#define NC    200
#define CPAD  256
#define KSTEP 32
#define NSTEP (DIMS / KSTEP)   // 24
#define ROWSB 64               // M-tile rows per block

typedef __attribute__((ext_vector_type(8))) short short8;   // 8 bf16
typedef __attribute__((ext_vector_type(4))) float f32x4;

__device__ __forceinline__ unsigned pk_bf16(float lo, float hi) {
  union { __hip_bfloat162 h; unsigned u; } c;
  c.h = __float22bfloat162_rn(make_float2(lo, hi));
  return c.u;
}

// Kernel 1: L2-normalize centers -> bf16, K-blocked layout:
// (c,d) -> cnb2[(d>>5)*CPAD*KSTEP + c*KSTEP + (d&31)]; rows >= NC zero.
// Also zeroes the output scalar.
__global__ __launch_bounds__(256) void prep_centers_k(const float* __restrict__ centers,
                                                      short* __restrict__ cnb2,
                                                      float* __restrict__ out) {
  const int c = blockIdx.x;
  const int tid = threadIdx.x;
  if (c == 0 && tid == 0) out[0] = 0.f;
  if (c >= NC) {
    for (int d = tid; d < DIMS; d += 256)
      cnb2[(d >> 5) * (CPAD * KSTEP) + c * KSTEP + (d & 31)] = 0;
    return;
  }
  float ssq = 0.f;
  for (int d = tid; d < DIMS; d += 256) {
    float v = centers[c * DIMS + d];
    ssq += v * v;
  }
#pragma unroll
  for (int off = 32; off > 0; off >>= 1) ssq += __shfl_down(ssq, off);
  __shared__ float red[4];
  const int wid = tid >> 6, lane = tid & 63;
  if (lane == 0) red[wid] = ssq;
  __syncthreads();
  const float tot = red[0] + red[1] + red[2] + red[3];
  const float inv = 1.f / fmaxf(sqrtf(tot), 1e-8f);
  for (int d = tid; d < DIMS; d += 256) {
    const float v = centers[c * DIMS + d] * inv;
    union { __hip_bfloat16 h; short s; } cv;
    cv.h = __float2bfloat16(v);
    cnb2[(d >> 5) * (CPAD * KSTEP) + c * KSTEP + (d & 31)] = cv.s;
  }
}

// Kernel 2: dbuf LDS GEMM with DEPTH-2 register prefetch:
//   iteration s: issue global loads for step s+2 | ds_write step s+1 | MFMA step s
// Load -> ds_write distance = one full K-step (> HBM latency ~900 cyc).
// LDS tiles: 64-B rows, quad-XOR swizzle ((idx>>1)&3) on write and read.
// MFMA frag mapping (verified rounds 2-6): A lane=A[m][kg*8+j]; B lane=B[kg*8+j][m];
// D: col=m, row=kg*4+reg.
__global__ __launch_bounds__(256) void cos_loss_k(
    const float* __restrict__ feats,
    const short* __restrict__ cnb2,
    const int* __restrict__ labels,
    const int* __restrict__ labelled,
    float* __restrict__ out) {
  const int tid = threadIdx.x;
  const int w = tid >> 6;            // wave id = column group (64 cols)
  const int lane = tid & 63;
  const int m = lane & 15;
  const int kg = lane >> 4;
  const int swzf = (m >> 1) & 3;     // frag-read quad swizzle
  const int rowBase = blockIdx.x * ROWSB;

  __shared__ short As[2][ROWSB][32];   // 8 KB
  __shared__ short Bs[2][CPAD][32];    // 32 KB
  __shared__ float invs[ROWSB];
  __shared__ int   labLds[ROWSB];
  __shared__ int   lblLds[ROWSB];
  __shared__ float l1part[4][ROWSB];
  __shared__ float alpart[4][ROWSB];

  if (tid < ROWSB) {
    labLds[tid] = labels[rowBase + tid];
    lblLds[tid] = labelled[rowBase + tid];
  }

  // staging assignments
  const int arow = tid >> 2;           // A: 4 thr/row, one b128 quad each
  const int akg  = tid & 3;
  const int aswz = (arow >> 1) & 3;
  const float* asrc = feats + (size_t)(rowBase + arow) * DIMS + akg * 8;
  const int bcol = tid;                // B: thread -> col, 64 B contiguous in cnb2
  const int bswz = (bcol >> 1) & 3;
  const short* bsrc = cnb2 + bcol * KSTEP;

  f32x4 acc[4][4];
#pragma unroll
  for (int mi = 0; mi < 4; ++mi)
#pragma unroll
    for (int ni = 0; ni < 4; ++ni) acc[mi][ni] = (f32x4){0.f, 0.f, 0.f, 0.f};

  float ssq = 0.f;

  // two named prefetch slots (all indices compile-time static)
  float4 S0_alo, S0_ahi; short8 S0_b0, S0_b1, S0_b2, S0_b3;
  float4 S1_alo, S1_ahi; short8 S1_b0, S1_b1, S1_b2, S1_b3;

#define LOAD_SLOT(P, step) do {                                          \
    const float* ap_ = asrc + (step) * KSTEP;                            \
    P##_alo = *(const float4*)(ap_);                                     \
    P##_ahi = *(const float4*)(ap_ + 4);                                 \
    const short* bp_ = bsrc + (size_t)(step) * (CPAD * KSTEP);           \
    P##_b0 = *(const short8*)(bp_ + 0);                                  \
    P##_b1 = *(const short8*)(bp_ + 8);                                  \
    P##_b2 = *(const short8*)(bp_ + 16);                                 \
    P##_b3 = *(const short8*)(bp_ + 24);                                 \
  } while (0)

#define WRITE_SLOT(P, buf) do {                                          \
    ssq += P##_alo.x*P##_alo.x + P##_alo.y*P##_alo.y                     \
         + P##_alo.z*P##_alo.z + P##_alo.w*P##_alo.w;                    \
    ssq += P##_ahi.x*P##_ahi.x + P##_ahi.y*P##_ahi.y                     \
         + P##_ahi.z*P##_ahi.z + P##_ahi.w*P##_ahi.w;                    \
    union { short8 s; unsigned u[4]; } p_;                               \
    p_.u[0] = pk_bf16(P##_alo.x, P##_alo.y);                             \
    p_.u[1] = pk_bf16(P##_alo.z, P##_alo.w);                             \
    p_.u[2] = pk_bf16(P##_ahi.x, P##_ahi.y);                             \
    p_.u[3] = pk_bf16(P##_ahi.z, P##_ahi.w);                             \
    *(short8*)(&As[(buf)][arow][(akg ^ aswz) * 8]) = p_.s;               \
    *(short8*)(&Bs[(buf)][bcol][(0 ^ bswz) * 8]) = P##_b0;               \
    *(short8*)(&Bs[(buf)][bcol][(1 ^ bswz) * 8]) = P##_b1;               \
    *(short8*)(&Bs[(buf)][bcol][(2 ^ bswz) * 8]) = P##_b2;               \
    *(short8*)(&Bs[(buf)][bcol][(3 ^ bswz) * 8]) = P##_b3;               \
  } while (0)

#define COMPUTE(buf) do {                                                \
    short8 af[4], bf[4];                                                 \
    _Pragma("unroll")                                                    \
    for (int mi = 0; mi < 4; ++mi)                                       \
      af[mi] = *(const short8*)(&As[(buf)][mi * 16 + m][(kg ^ swzf) * 8]); \
    _Pragma("unroll")                                                    \
    for (int ni = 0; ni < 4; ++ni)                                       \
      bf[ni] = *(const short8*)(&Bs[(buf)][w * 64 + ni * 16 + m][(kg ^ swzf) * 8]); \
    _Pragma("unroll")                                                    \
    for (int mi = 0; mi < 4; ++mi)                                       \
      _Pragma("unroll")                                                  \
      for (int ni = 0; ni < 4; ++ni)                                     \
        acc[mi][ni] = __builtin_amdgcn_mfma_f32_16x16x32_bf16(           \
            af[mi], bf[ni], acc[mi][ni], 0, 0, 0);                       \
  } while (0)

  // prologue: step0 -> buf0 (immediate), step1 -> slot1 (in flight)
  LOAD_SLOT(S0, 0);
  WRITE_SLOT(S0, 0);
  LOAD_SLOT(S1, 1);
  __syncthreads();

  for (int ks = 0; ks < NSTEP; ks += 2) {
    // even phase: compute step ks from buf0
    if (ks + 2 < NSTEP) LOAD_SLOT(S0, ks + 2);
    WRITE_SLOT(S1, 1);                    // step ks+1 -> buf1 (loaded a full phase ago)
    COMPUTE(0);
    __syncthreads();
    // odd phase: compute step ks+1 from buf1
    if (ks + 3 < NSTEP) LOAD_SLOT(S1, ks + 3);
    if (ks + 2 < NSTEP) WRITE_SLOT(S0, 0); // step ks+2 -> buf0
    COMPUTE(1);
    __syncthreads();
  }

#undef LOAD_SLOT
#undef WRITE_SLOT
#undef COMPUTE

  // ---- row inverse norms (fp32) ----
  ssq += __shfl_xor(ssq, 1);
  ssq += __shfl_xor(ssq, 2);
  if ((tid & 3) == 0) invs[arow] = 1.f / fmaxf(sqrtf(ssq), 1e-8f);
  __syncthreads();

  // ---- epilogue: per-row l1 and label-|cos| ----
#pragma unroll
  for (int mi = 0; mi < 4; ++mi) {
    float l1r[4] = {0.f, 0.f, 0.f, 0.f};
    float alr[4] = {0.f, 0.f, 0.f, 0.f};
    float iv[4];
    int labr[4];
#pragma unroll
    for (int r = 0; r < 4; ++r) {
      const int row = mi * 16 + kg * 4 + r;
      iv[r] = invs[row];
      labr[r] = labLds[row];
    }
#pragma unroll
    for (int ni = 0; ni < 4; ++ni) {
      const int col = w * 64 + ni * 16 + m;
#pragma unroll
      for (int r = 0; r < 4; ++r) {
        const float a = fabsf(acc[mi][ni][r] * iv[r]);
        l1r[r] += a;
        if (col == labr[r]) alr[r] += a;
      }
    }
#pragma unroll
    for (int r = 0; r < 4; ++r) {
#pragma unroll
      for (int off = 1; off < 16; off <<= 1) {
        l1r[r] += __shfl_xor(l1r[r], off);
        alr[r] += __shfl_xor(alr[r], off);
      }
    }
    if (m == 0) {
#pragma unroll
      for (int r = 0; r < 4; ++r) {
        l1part[w][mi * 16 + kg * 4 + r] = l1r[r];
        alpart[w][mi * 16 + kg * 4 + r] = alr[r];
      }
    }
  }
  __syncthreads();

  if (tid < ROWSB) {
    const float L = l1part[0][tid] + l1part[1][tid] + l1part[2][tid] + l1part[3][tid];
    const float A = alpart[0][tid] + alpart[1][tid] + alpart[2][tid] + alpart[3][tid];
    float c = lblLds[tid] ? (L - 2.f * A) / fmaxf(L, 1e-12f) : 0.f;
#pragma unroll
    for (int off = 1; off < 64; off <<= 1) c += __shfl_xor(c, off);
    if (tid == 0) atomicAdd(out, c);
  }
}

extern "C" void kernel_launch(void* const* d_in, const int* in_sizes, int n_in,
                              void* d_out, int out_size, void* d_ws, size_t ws_size,
                              hipStream_t stream) {
  const float* feats = (const float*)d_in[0];
  const float* centers = (const float*)d_in[1];
  const int* labels = (const int*)d_in[2];
  const int* labelled = (const int*)d_in[3];
  float* out = (float*)d_out;
  short* cnb2 = (short*)d_ws;  // [24][256][32] bf16 = 393216 B

  prep_centers_k<<<CPAD, 256, 0, stream>>>(centers, cnb2, out);
  cos_loss_k<<<NROWS / ROWSB, 256, 0, stream>>>(feats, cnb2, labels, labelled, out);
}